// Round 6
// baseline (178.934 us; speedup 1.0000x reference)
//
#include <hip/hip_runtime.h>
#include <stdint.h>

// ---- types ----
typedef _Float16 f16x8 __attribute__((ext_vector_type(8)));
typedef _Float16 f16x4 __attribute__((ext_vector_type(4)));
typedef __fp16 h16x2 __attribute__((ext_vector_type(2)));  // cvt_pkrtz return type
typedef float f32x4 __attribute__((ext_vector_type(4)));

#define SEQ 2048
#define NHEADS 8

// async global->LDS, 16B per lane, LDS dest = wave-uniform base + lane*16
#define GLOAD_LDS16(gp, lp)                                                        \
  __builtin_amdgcn_global_load_lds(                                                \
      (const __attribute__((address_space(1))) void*)(uintptr_t)(const void*)(gp), \
      (__attribute__((address_space(3))) void*)(uintptr_t)(void*)(lp), 16, 0, 0)

// barrier that waits LDS ops only -- global loads stay in flight (AITER-style)
__device__ __forceinline__ void barrier_lds() {
  __builtin_amdgcn_s_waitcnt(0xc07f);  // lgkmcnt(0), vmcnt/expcnt untouched
  __builtin_amdgcn_s_barrier();
}

__device__ __forceinline__ f16x4 pack4(float a, float b, float c, float d) {
  h16x2 lo = __builtin_amdgcn_cvt_pkrtz(a, b);
  h16x2 hi = __builtin_amdgcn_cvt_pkrtz(c, d);
  f16x4 o;
  o.x = (_Float16)lo.x; o.y = (_Float16)lo.y;
  o.z = (_Float16)hi.x; o.w = (_Float16)hi.y;
  return o;
}

// ---------------- fp32 -> f16 convert (x + 4 weights, one launch) ----------------
__global__ void cvt_all_kernel(const float* __restrict__ x, const float* __restrict__ wq,
                               const float* __restrict__ wk, const float* __restrict__ wv,
                               const float* __restrict__ wo, _Float16* __restrict__ xh,
                               _Float16* __restrict__ wh) {
  int i = blockIdx.x * 256 + threadIdx.x;  // 0 .. 1310719 (f4 units)
  const float* src;
  _Float16* dst;
  int off;
  if (i < 1048576) {
    src = x; dst = xh; off = i;
  } else {
    int j = i - 1048576;
    int sel = j >> 16;
    off = j & 65535;
    src = (sel == 0) ? wq : (sel == 1) ? wk : (sel == 2) ? wv : wo;
    dst = wh + (size_t)sel * 262144;
  }
  float4 v = ((const float4*)src)[off];
  ((f16x4*)dst)[off] = pack4(v.x, v.y, v.z, v.w);
}

// ---------------- shared 128x128 B^T GEMM tile core (f16) ----------------
__device__ __forceinline__ void gemm_tile_bt(const _Float16* __restrict__ A,
                                             const _Float16* __restrict__ B,
                                             int m0, int n0,
                                             _Float16* As, _Float16* Bs,
                                             f32x4 (&acc)[4][4]) {
  const int tid = threadIdx.x;
  const int w = tid >> 6, lane = tid & 63;
  const int wr = w >> 1, wc = w & 1;
  const int lrow = lane & 15, q = lane >> 4;
  const int snb = w * 32 + (lane >> 3);
  const int scb = lane & 7;

#pragma unroll
  for (int i = 0; i < 4; ++i)
#pragma unroll
    for (int j = 0; j < 4; ++j)
#pragma unroll
      for (int r = 0; r < 4; ++r) acc[i][j][r] = 0.f;

  for (int kt = 0; kt < 8; ++kt) {  // K=512, BK=64
    __syncthreads();
#pragma unroll
    for (int t = 0; t < 4; ++t) {
      int n = snb + t * 8;
      int cbg = scb ^ (n & 7);
      GLOAD_LDS16(A + (size_t)(m0 + n) * 512 + kt * 64 + cbg * 8,
                  As + (w * 32 + t * 8) * 64);
      GLOAD_LDS16(B + (size_t)(n0 + n) * 512 + kt * 64 + cbg * 8,
                  Bs + (w * 32 + t * 8) * 64);
    }
    __syncthreads();

    f16x8 af[4][2], bfr[4][2];
#pragma unroll
    for (int i = 0; i < 4; ++i) {
      int m = wr * 64 + i * 16 + lrow;
#pragma unroll
      for (int kk = 0; kk < 2; ++kk) {
        int cb = (kk * 4 + q) ^ (m & 7);
        af[i][kk] = *(const f16x8*)(As + m * 64 + cb * 8);
      }
    }
#pragma unroll
    for (int j = 0; j < 4; ++j) {
      int n = wc * 64 + j * 16 + lrow;
#pragma unroll
      for (int kk = 0; kk < 2; ++kk) {
        int cb = (kk * 4 + q) ^ (n & 7);
        bfr[j][kk] = *(const f16x8*)(Bs + n * 64 + cb * 8);
      }
    }
#pragma unroll
    for (int i = 0; i < 4; ++i)
#pragma unroll
      for (int j = 0; j < 4; ++j) {
        acc[i][j] = __builtin_amdgcn_mfma_f32_16x16x32_f16(af[i][0], bfr[j][0], acc[i][j], 0, 0, 0);
        acc[i][j] = __builtin_amdgcn_mfma_f32_16x16x32_f16(af[i][1], bfr[j][1], acc[i][j], 0, 0, 0);
      }
  }
}

// ---------------- QKV projection (round-4 structure: 768 blocks, 2+/CU) ----------------
__global__ __launch_bounds__(256, 2) void qkv_kernel(
    const _Float16* __restrict__ xb, const _Float16* __restrict__ Wq,
    const _Float16* __restrict__ Wk, const _Float16* __restrict__ Wv,
    _Float16* __restrict__ Qo, _Float16* __restrict__ Ko, _Float16* __restrict__ Vto) {
  __shared__ _Float16 pool[17408];  // 34.8 KB: staging (32KB) then bounce [128][136]
  _Float16* As = pool;
  _Float16* Bs = pool + 8192;
  const int z = blockIdx.z;
  f32x4 acc[4][4];
  const int tid = threadIdx.x, w = tid >> 6, lane = tid & 63;
  const int wr = w >> 1, wc = w & 1, lcol = lane & 15, q = lane >> 4;

  if (z < 2) {
    const int m0 = blockIdx.y * 128;  // out-feature tile
    const int n0 = blockIdx.x * 128;  // s tile
    gemm_tile_bt((z == 0) ? Wq : Wk, xb, m0, n0, As, Bs, acc);
    _Float16* outp = (z == 0) ? Qo : Ko;
    __syncthreads();  // staging reads done; reuse pool as bounce [s 128][c 136]
#pragma unroll
    for (int i = 0; i < 4; ++i) {
      int cl = wr * 64 + i * 16 + q * 4;
#pragma unroll
      for (int j = 0; j < 4; ++j) {
        int s = wc * 64 + j * 16 + lcol;
        *(f16x4*)(pool + s * 136 + cl) =
            pack4(acc[i][j][0], acc[i][j][1], acc[i][j][2], acc[i][j][3]);
      }
    }
    __syncthreads();
#pragma unroll
    for (int it = 0; it < 16; ++it) {
      int srow = it * 8 + (tid >> 5);
      int ch = tid & 31;
      f16x4 v = *(const f16x4*)(pool + srow * 136 + ch * 4);
      *(f16x4*)(outp + (size_t)(n0 + srow) * 512 + m0 + ch * 4) = v;
    }
  } else {
    const int m0 = blockIdx.x * 128;  // s tile
    const int n0 = blockIdx.y * 128;  // feature tile
    gemm_tile_bt(xb, Wv, m0, n0, As, Bs, acc);
    const int bb = m0 >> 11, sl0 = m0 & 2047;
    __syncthreads();  // bounce [c 128][s 136]
#pragma unroll
    for (int i = 0; i < 4; ++i) {
      int s0 = wr * 64 + i * 16 + q * 4;
#pragma unroll
      for (int j = 0; j < 4; ++j) {
        int c = wc * 64 + j * 16 + lcol;
        *(f16x4*)(pool + c * 136 + s0) =
            pack4(acc[i][j][0], acc[i][j][1], acc[i][j][2], acc[i][j][3]);
      }
    }
    __syncthreads();
#pragma unroll
    for (int it = 0; it < 16; ++it) {
      int crow = it * 8 + (tid >> 5);
      int ch = tid & 31;
      int cg = n0 + crow, h = cg >> 6, d = cg & 63;
      f16x4 v = *(const f16x4*)(pool + crow * 136 + ch * 4);
      *(f16x4*)(Vto + ((size_t)((bb * NHEADS + h) * 64 + d)) * SEQ + sl0 + ch * 4) = v;
    }
  }
}

// ---------------- sigmoid attention: register K/V, LDS = Ps only ----------------
// 512 blocks, 32KB LDS. K/V fragments loaded straight from L2 to VGPRs; loads
// stay in flight across raw-lgkm barriers (no vmcnt drain per k-tile).
__global__ __launch_bounds__(256, 2) void attn_kernel(
    const _Float16* __restrict__ Qw, const _Float16* __restrict__ Kw,
    const _Float16* __restrict__ Vtw, _Float16* __restrict__ Ow) {
  __shared__ _Float16 lds[16384];  // 32 KB: Ps [128][128]; aliases Qs, O-bounce
  _Float16* Ps = lds;
  _Float16* Qs = lds;

  const int tid = threadIdx.x, w = tid >> 6, lane = tid & 63;
  const int wr = w >> 1, wc = w & 1, lrow = lane & 15, q = lane >> 4;

  // XCD swizzle: 4 bh x 16 q-tiles per XCD (K/V stay L2-resident)
  const int L = blockIdx.x;
  const int xcd = L & 7, slot = L >> 3;
  const int bh = xcd * 4 + (slot >> 4), qt = slot & 15;
  const int b = bh >> 3, h = bh & 7;
  const int q0 = qt * 128;

  const _Float16* Qp = Qw + ((size_t)(b * SEQ + q0)) * 512 + h * 64;
  // per-thread invariant K/V bases
  const _Float16* Kt = Kw + ((size_t)b * SEQ) * 512 + h * 64 +
                       (size_t)(wc * 64 + lrow) * 512 + q * 8;
  const _Float16* Vt = Vtw + (size_t)bh * 64 * SEQ +
                       (size_t)(wc * 32 + lrow) * SEQ + q * 8;

  // stage Q tile [128][64] into Qs (=Ps region)
  const int snb = w * 32 + (lane >> 3), scb = lane & 7;
#pragma unroll
  for (int t = 0; t < 4; ++t) {
    int n = snb + t * 8;
    int cbg = scb ^ (n & 7);
    GLOAD_LDS16(Qp + (size_t)n * 512 + cbg * 8, Qs + (w * 32 + t * 8) * 64);
  }
  __syncthreads();  // staging landed (vmcnt drain needed once)

  f16x8 qa[4][2];
#pragma unroll
  for (int i = 0; i < 4; ++i) {
    int m = wr * 64 + i * 16 + lrow;
#pragma unroll
    for (int kk = 0; kk < 2; ++kk) {
      int cb = (kk * 4 + q) ^ (m & 7);
      qa[i][kk] = *(const f16x8*)(Qs + m * 64 + cb * 8);
    }
  }

  // K fragments for kt=0
  f16x8 kb[4][2];
#pragma unroll
  for (int j = 0; j < 4; ++j)
#pragma unroll
    for (int kk = 0; kk < 2; ++kk)
      kb[j][kk] = *(const f16x8*)(Kt + (size_t)(j * 16) * 512 + kk * 32);

  barrier_lds();  // all qa reads done before Ps overwrite

  f32x4 oacc[4][2];
#pragma unroll
  for (int i = 0; i < 4; ++i)
#pragma unroll
    for (int j = 0; j < 2; ++j)
#pragma unroll
      for (int r = 0; r < 4; ++r) oacc[i][j][r] = 0.f;

  const float c1 = 0.18033688011112042f;  // (1/8)*log2(e); exp2 bias -1 = -11+10 (P x1024)

  for (int kt = 0; kt < 16; ++kt) {
    // V fragments for this kt (consumed after the barrier; latency hidden by QK+sigmoid)
    f16x8 vb[2][4];
#pragma unroll
    for (int j2 = 0; j2 < 2; ++j2)
#pragma unroll
      for (int ks = 0; ks < 4; ++ks)
        vb[j2][ks] = *(const f16x8*)(Vt + (size_t)(j2 * 16) * SEQ + kt * 128 + ks * 32);

    // S^T = K·Q^T (C rows = k-col quad/reg axis, cols = q-row lane axis)
    f32x4 st[4][4];
#pragma unroll
    for (int j = 0; j < 4; ++j)
#pragma unroll
      for (int i = 0; i < 4; ++i)
#pragma unroll
        for (int r = 0; r < 4; ++r) st[j][i][r] = 0.f;
#pragma unroll
    for (int j = 0; j < 4; ++j)
#pragma unroll
      for (int i = 0; i < 4; ++i) {
        st[j][i] = __builtin_amdgcn_mfma_f32_16x16x32_f16(kb[j][0], qa[i][0], st[j][i], 0, 0, 0);
        st[j][i] = __builtin_amdgcn_mfma_f32_16x16x32_f16(kb[j][1], qa[i][1], st[j][i], 0, 0, 0);
      }

    // K fragments for next kt (in flight across both barriers, consumed next iter)
    {
      int ktn = (kt + 1) & 15;
#pragma unroll
      for (int j = 0; j < 4; ++j)
#pragma unroll
        for (int kk = 0; kk < 2; ++kk)
          kb[j][kk] = *(const f16x8*)(Kt + (size_t)(ktn * 128 + j * 16) * 512 + kk * 32);
    }

    // sigmoid: p' = 1024*sigmoid(qk/8 - ln2048); packed b64 writes into Ps
#pragma unroll
    for (int i = 0; i < 4; ++i) {
      int qrow = wr * 64 + i * 16 + lrow;
#pragma unroll
      for (int j = 0; j < 4; ++j) {
        int kbase = wc * 64 + j * 16 + q * 4;
        float p[4];
#pragma unroll
        for (int r = 0; r < 4; ++r) {
          float wp = __builtin_amdgcn_exp2f(__builtin_fmaf(st[j][i][r], c1, -1.0f));
          float e = wp * 0.0009765625f;
          float s1 = __builtin_fmaf(e, e, -e);  // e^2 - e
          p[r] = __builtin_fmaf(wp, s1, wp);    // wp*(1 - e + e^2)
        }
        int kb8 = kbase >> 3;
        *(f16x4*)(Ps + qrow * 128 + ((kb8 ^ (qrow & 15)) << 3) + (kbase & 7)) =
            pack4(p[0], p[1], p[2], p[3]);
      }
    }
    barrier_lds();  // Ps complete (lgkm only -- kb/vb loads stay in flight)

    // O += P @ V  (M=128,N=64,K=128); V from registers
#pragma unroll
    for (int ks = 0; ks < 4; ++ks) {
      f16x8 pa[4];
#pragma unroll
      for (int i2 = 0; i2 < 4; ++i2) {
        int m = wr * 64 + i2 * 16 + lrow;
        int cb = (ks * 4 + q) ^ (m & 15);
        pa[i2] = *(const f16x8*)(Ps + m * 128 + cb * 8);
      }
#pragma unroll
      for (int i2 = 0; i2 < 4; ++i2)
#pragma unroll
        for (int j2 = 0; j2 < 2; ++j2)
          oacc[i2][j2] = __builtin_amdgcn_mfma_f32_16x16x32_f16(pa[i2], vb[j2][ks], oacc[i2][j2], 0, 0, 0);
    }
    barrier_lds();  // Ps reads done before next overwrite
  }

  // epilogue: descale, bounce through Ps region, coalesced 128B row stores
  _Float16* Ob = Ps;  // [128][72]
#pragma unroll
  for (int i2 = 0; i2 < 4; ++i2) {
#pragma unroll
    for (int j2 = 0; j2 < 2; ++j2) {
      int d = wc * 32 + j2 * 16 + lrow;
#pragma unroll
      for (int r = 0; r < 4; ++r) {
        int row = wr * 64 + i2 * 16 + q * 4 + r;
        Ob[row * 72 + d] = (_Float16)(oacc[i2][j2][r] * 0.0009765625f);
      }
    }
  }
  barrier_lds();
#pragma unroll
  for (int it = 0; it < 8; ++it) {
    int row = it * 16 + (tid >> 4);
    int ch = tid & 15;
    f16x4 v = *(const f16x4*)(Ob + row * 72 + ch * 4);
    *(f16x4*)(Ow + (size_t)(b * SEQ + q0 + row) * 512 + h * 64 + ch * 4) = v;
  }
}

// ---------------- output projection (fp32 out, coalesced) ----------------
__global__ __launch_bounds__(256, 2) void oproj_kernel(
    const _Float16* __restrict__ A, const _Float16* __restrict__ Wo,
    float* __restrict__ out) {
  __shared__ _Float16 As[128 * 64];
  __shared__ _Float16 Bs[128 * 64];
  const int m0 = blockIdx.x * 128, n0 = blockIdx.y * 128;
  f32x4 acc[4][4];
  gemm_tile_bt(A, Wo, m0, n0, As, Bs, acc);

  const int tid = threadIdx.x, w = tid >> 6, lane = tid & 63;
  const int wr = w >> 1, wc = w & 1, lcol = lane & 15, q = lane >> 4;
#pragma unroll
  for (int i = 0; i < 4; ++i) {
    int gm0 = m0 + wr * 64 + i * 16 + q * 4;
#pragma unroll
    for (int j = 0; j < 4; ++j) {
      int gn = n0 + wc * 64 + j * 16 + lcol;
#pragma unroll
      for (int r = 0; r < 4; ++r)
        out[(size_t)(gm0 + r) * 512 + gn] = acc[i][j][r];
    }
  }
}

// ---------------- launch ----------------
extern "C" void kernel_launch(void* const* d_in, const int* in_sizes, int n_in,
                              void* d_out, int out_size, void* d_ws, size_t ws_size,
                              hipStream_t stream) {
  const float* x = (const float*)d_in[0];
  const float* Wq = (const float*)d_in[1];
  const float* Wk = (const float*)d_in[2];
  const float* Wv = (const float*)d_in[3];
  const float* Wo = (const float*)d_in[4];
  float* out = (float*)d_out;
  char* ws = (char*)d_ws;

  _Float16* xh = (_Float16*)(ws + 0);          // 8 MB [8192][512]
  _Float16* wh = (_Float16*)(ws + 8388608);    // 4 x 512 KB (q,k,v,o)
  _Float16* Qw = (_Float16*)(ws + 10485760);   // 8 MB [8192][512]
  _Float16* Kw = (_Float16*)(ws + 18874368);   // 8 MB [8192][512]
  _Float16* Vtw = (_Float16*)(ws + 27262976);  // 8 MB [B,H,D,S]
  _Float16* Ow = (_Float16*)(ws + 35651584);   // 8 MB [8192][512]

  _Float16* wqh = wh;
  _Float16* wkh = wh + 262144;
  _Float16* wvh = wh + 524288;
  _Float16* woh = wh + 786432;

  cvt_all_kernel<<<5120, 256, 0, stream>>>(x, Wq, Wk, Wv, Wo, xh, wh);
  qkv_kernel<<<dim3(64, 4, 3), 256, 0, stream>>>(xh, wqh, wkh, wvh, Qw, Kw, Vtw);
  attn_kernel<<<512, 256, 0, stream>>>(Qw, Kw, Vtw, Ow);
  oproj_kernel<<<dim3(64, 4), 256, 0, stream>>>(Ow, woh, out);
}

// Round 7
// 153.041 us; speedup vs baseline: 1.1692x; 1.1692x over previous
//
#include <hip/hip_runtime.h>
#include <stdint.h>

// ---- types ----
typedef _Float16 f16x8 __attribute__((ext_vector_type(8)));
typedef _Float16 f16x4 __attribute__((ext_vector_type(4)));
typedef __fp16 h16x2 __attribute__((ext_vector_type(2)));  // cvt_pkrtz return type
typedef float f32x4 __attribute__((ext_vector_type(4)));

#define SEQ 2048
#define NHEADS 8

// async global->LDS, 16B per lane, LDS dest = wave-uniform base + lane*16
#define GLOAD_LDS16(gp, lp)                                                        \
  __builtin_amdgcn_global_load_lds(                                                \
      (const __attribute__((address_space(1))) void*)(uintptr_t)(const void*)(gp), \
      (__attribute__((address_space(3))) void*)(uintptr_t)(void*)(lp), 16, 0, 0)

// barrier that waits LDS ops only (no vmem drain)
__device__ __forceinline__ void barrier_lds() {
  __builtin_amdgcn_s_waitcnt(0xc07f);  // lgkmcnt(0)
  __builtin_amdgcn_s_barrier();
}

__device__ __forceinline__ f16x4 pack4(float a, float b, float c, float d) {
  h16x2 lo = __builtin_amdgcn_cvt_pkrtz(a, b);
  h16x2 hi = __builtin_amdgcn_cvt_pkrtz(c, d);
  f16x4 o;
  o.x = (_Float16)lo.x; o.y = (_Float16)lo.y;
  o.z = (_Float16)hi.x; o.w = (_Float16)hi.y;
  return o;
}

// ---------------- fp32 -> f16 convert (x + 4 weights, one launch) ----------------
__global__ void cvt_all_kernel(const float* __restrict__ x, const float* __restrict__ wq,
                               const float* __restrict__ wk, const float* __restrict__ wv,
                               const float* __restrict__ wo, _Float16* __restrict__ xh,
                               _Float16* __restrict__ wh) {
  int i = blockIdx.x * 256 + threadIdx.x;  // 0 .. 1310719 (f4 units)
  const float* src;
  _Float16* dst;
  int off;
  if (i < 1048576) {
    src = x; dst = xh; off = i;
  } else {
    int j = i - 1048576;
    int sel = j >> 16;
    off = j & 65535;
    src = (sel == 0) ? wq : (sel == 1) ? wk : (sel == 2) ? wv : wo;
    dst = wh + (size_t)sel * 262144;
  }
  float4 v = ((const float4*)src)[off];
  ((f16x4*)dst)[off] = pack4(v.x, v.y, v.z, v.w);
}

// ---------------- shared 128x128 B^T GEMM tile core (f16) ----------------
__device__ __forceinline__ void gemm_tile_bt(const _Float16* __restrict__ A,
                                             const _Float16* __restrict__ B,
                                             int m0, int n0,
                                             _Float16* As, _Float16* Bs,
                                             f32x4 (&acc)[4][4]) {
  const int tid = threadIdx.x;
  const int w = tid >> 6, lane = tid & 63;
  const int wr = w >> 1, wc = w & 1;
  const int lrow = lane & 15, q = lane >> 4;
  const int snb = w * 32 + (lane >> 3);
  const int scb = lane & 7;

#pragma unroll
  for (int i = 0; i < 4; ++i)
#pragma unroll
    for (int j = 0; j < 4; ++j)
#pragma unroll
      for (int r = 0; r < 4; ++r) acc[i][j][r] = 0.f;

  for (int kt = 0; kt < 8; ++kt) {  // K=512, BK=64
    __syncthreads();
#pragma unroll
    for (int t = 0; t < 4; ++t) {
      int n = snb + t * 8;
      int cbg = scb ^ (n & 7);
      GLOAD_LDS16(A + (size_t)(m0 + n) * 512 + kt * 64 + cbg * 8,
                  As + (w * 32 + t * 8) * 64);
      GLOAD_LDS16(B + (size_t)(n0 + n) * 512 + kt * 64 + cbg * 8,
                  Bs + (w * 32 + t * 8) * 64);
    }
    __syncthreads();

    f16x8 af[4][2], bfr[4][2];
#pragma unroll
    for (int i = 0; i < 4; ++i) {
      int m = wr * 64 + i * 16 + lrow;
#pragma unroll
      for (int kk = 0; kk < 2; ++kk) {
        int cb = (kk * 4 + q) ^ (m & 7);
        af[i][kk] = *(const f16x8*)(As + m * 64 + cb * 8);
      }
    }
#pragma unroll
    for (int j = 0; j < 4; ++j) {
      int n = wc * 64 + j * 16 + lrow;
#pragma unroll
      for (int kk = 0; kk < 2; ++kk) {
        int cb = (kk * 4 + q) ^ (n & 7);
        bfr[j][kk] = *(const f16x8*)(Bs + n * 64 + cb * 8);
      }
    }
#pragma unroll
    for (int i = 0; i < 4; ++i)
#pragma unroll
      for (int j = 0; j < 4; ++j) {
        acc[i][j] = __builtin_amdgcn_mfma_f32_16x16x32_f16(af[i][0], bfr[j][0], acc[i][j], 0, 0, 0);
        acc[i][j] = __builtin_amdgcn_mfma_f32_16x16x32_f16(af[i][1], bfr[j][1], acc[i][j], 0, 0, 0);
      }
  }
}

// ---------------- QKV projection (round-4: 768 blocks, coalesced bounce epilogues) ----------------
__global__ __launch_bounds__(256, 2) void qkv_kernel(
    const _Float16* __restrict__ xb, const _Float16* __restrict__ Wq,
    const _Float16* __restrict__ Wk, const _Float16* __restrict__ Wv,
    _Float16* __restrict__ Qo, _Float16* __restrict__ Ko, _Float16* __restrict__ Vto) {
  __shared__ _Float16 pool[17408];  // 34.8 KB: staging (32KB) then bounce [128][136]
  _Float16* As = pool;
  _Float16* Bs = pool + 8192;
  const int z = blockIdx.z;
  f32x4 acc[4][4];
  const int tid = threadIdx.x, w = tid >> 6, lane = tid & 63;
  const int wr = w >> 1, wc = w & 1, lcol = lane & 15, q = lane >> 4;

  if (z < 2) {
    const int m0 = blockIdx.y * 128;  // out-feature tile
    const int n0 = blockIdx.x * 128;  // s tile
    gemm_tile_bt((z == 0) ? Wq : Wk, xb, m0, n0, As, Bs, acc);
    _Float16* outp = (z == 0) ? Qo : Ko;
    __syncthreads();
#pragma unroll
    for (int i = 0; i < 4; ++i) {
      int cl = wr * 64 + i * 16 + q * 4;
#pragma unroll
      for (int j = 0; j < 4; ++j) {
        int s = wc * 64 + j * 16 + lcol;
        *(f16x4*)(pool + s * 136 + cl) =
            pack4(acc[i][j][0], acc[i][j][1], acc[i][j][2], acc[i][j][3]);
      }
    }
    __syncthreads();
#pragma unroll
    for (int it = 0; it < 16; ++it) {
      int srow = it * 8 + (tid >> 5);
      int ch = tid & 31;
      f16x4 v = *(const f16x4*)(pool + srow * 136 + ch * 4);
      *(f16x4*)(outp + (size_t)(n0 + srow) * 512 + m0 + ch * 4) = v;
    }
  } else {
    const int m0 = blockIdx.x * 128;  // s tile
    const int n0 = blockIdx.y * 128;  // feature tile
    gemm_tile_bt(xb, Wv, m0, n0, As, Bs, acc);
    const int bb = m0 >> 11, sl0 = m0 & 2047;
    __syncthreads();
#pragma unroll
    for (int i = 0; i < 4; ++i) {
      int s0 = wr * 64 + i * 16 + q * 4;
#pragma unroll
      for (int j = 0; j < 4; ++j) {
        int c = wc * 64 + j * 16 + lcol;
        *(f16x4*)(pool + c * 136 + s0) =
            pack4(acc[i][j][0], acc[i][j][1], acc[i][j][2], acc[i][j][3]);
      }
    }
    __syncthreads();
#pragma unroll
    for (int it = 0; it < 16; ++it) {
      int crow = it * 8 + (tid >> 5);
      int ch = tid & 31;
      int cg = n0 + crow, h = cg >> 6, d = cg & 63;
      f16x4 v = *(const f16x4*)(pool + crow * 136 + ch * 4);
      *(f16x4*)(Vto + ((size_t)((bb * NHEADS + h) * 64 + d)) * SEQ + sl0 + ch * 4) = v;
    }
  }
}

// ---------------- sigmoid attention: wave-owns-32-q-rows, 2 barriers/kt ----------------
// Each wave computes S^T (all 128 kcols) for ITS 32 q-rows, sigmoids into ITS Ps
// rows, and PVs ITS rows -- no block-wide sync between sigmoid and PV.
__global__ __launch_bounds__(256, 2) void attn_kernel(
    const _Float16* __restrict__ Qw, const _Float16* __restrict__ Kw,
    const _Float16* __restrict__ Vtw, _Float16* __restrict__ Ow) {
  __shared__ _Float16 lds[32768];  // 64 KB
  _Float16* Ps = lds;              // [128][128] 32KB; aliases Qs + O-bounce
  _Float16* Qs = lds;              // [128][64]
  _Float16* Ks = lds + 16384;      // [128][64]
  _Float16* Vts = lds + 24576;     // [64][128]

  const int tid = threadIdx.x, w = tid >> 6, lane = tid & 63;
  const int lrow = lane & 15, q = lane >> 4;

  // XCD swizzle: 4 bh x 16 q-tiles per XCD (K/V stay L2-resident)
  const int L = blockIdx.x;
  const int xcd = L & 7, slot = L >> 3;
  const int bh = xcd * 4 + (slot >> 4), qt = slot & 15;
  const int b = bh >> 3, h = bh & 7;
  const int q0 = qt * 128;

  const _Float16* Qp = Qw + ((size_t)(b * SEQ + q0)) * 512 + h * 64;
  const _Float16* Kp = Kw + ((size_t)b * SEQ) * 512 + h * 64;
  const _Float16* Vp = Vtw + (size_t)bh * 64 * SEQ;

  const int snb = w * 32 + (lane >> 3), scb = lane & 7;   // [128][64] staging
  const int vnb = w * 16 + (lane >> 4), vcb = lane & 15;  // [64][128] staging

  // stage Q tile [128][64] into Qs (=Ps region)
#pragma unroll
  for (int t = 0; t < 4; ++t) {
    int n = snb + t * 8;
    int cbg = scb ^ (n & 7);
    GLOAD_LDS16(Qp + (size_t)n * 512 + cbg * 8, Qs + (w * 32 + t * 8) * 64);
  }
  __syncthreads();

  // wave's own 32 q-rows
  f16x8 qa[2][2];
#pragma unroll
  for (int i = 0; i < 2; ++i) {
    int m = w * 32 + i * 16 + lrow;
#pragma unroll
    for (int kk = 0; kk < 2; ++kk) {
      int cb = (kk * 4 + q) ^ (m & 7);
      qa[i][kk] = *(const f16x8*)(Qs + m * 64 + cb * 8);
    }
  }
  barrier_lds();  // all qa reads done before any Ps overwrite

  f32x4 oacc[2][4];
#pragma unroll
  for (int i = 0; i < 2; ++i)
#pragma unroll
    for (int j = 0; j < 4; ++j)
#pragma unroll
      for (int r = 0; r < 4; ++r) oacc[i][j][r] = 0.f;

  const float c1 = 0.18033688011112042f;  // (1/8)*log2(e); exp2 bias -1 = -11+10 (P x1024)

  for (int kt = 0; kt < 16; ++kt) {
    barrier_lds();  // (a) all waves' Ks/Vts/Ps reads from kt-1 done (lgkm only)
#pragma unroll
    for (int t = 0; t < 4; ++t) {
      int n = snb + t * 8;
      int cbg = scb ^ (n & 7);
      GLOAD_LDS16(Kp + (size_t)(kt * 128 + n) * 512 + cbg * 8, Ks + (w * 32 + t * 8) * 64);
    }
#pragma unroll
    for (int t = 0; t < 4; ++t) {
      int nv = vnb + t * 4;
      int cbg = vcb ^ (nv & 15);
      GLOAD_LDS16(Vp + (size_t)nv * SEQ + kt * 128 + cbg * 8, Vts + (w * 16 + t * 4) * 128);
    }
    __syncthreads();  // (b) staging landed (the one unavoidable vmem drain)

    // QK^T (S^T form) + fused sigmoid, per 16-kcol block j
#pragma unroll
    for (int j = 0; j < 8; ++j) {
      int n = j * 16 + lrow;
      int cb0 = q ^ (n & 7), cb1 = (4 + q) ^ (n & 7);
      f16x8 k0 = *(const f16x8*)(Ks + n * 64 + cb0 * 8);
      f16x8 k1 = *(const f16x8*)(Ks + n * 64 + cb1 * 8);
      f32x4 s0, s1;
#pragma unroll
      for (int r = 0; r < 4; ++r) { s0[r] = 0.f; s1[r] = 0.f; }
      s0 = __builtin_amdgcn_mfma_f32_16x16x32_f16(k0, qa[0][0], s0, 0, 0, 0);
      s0 = __builtin_amdgcn_mfma_f32_16x16x32_f16(k1, qa[0][1], s0, 0, 0, 0);
      s1 = __builtin_amdgcn_mfma_f32_16x16x32_f16(k0, qa[1][0], s1, 0, 0, 0);
      s1 = __builtin_amdgcn_mfma_f32_16x16x32_f16(k1, qa[1][1], s1, 0, 0, 0);

      int kbase = j * 16 + q * 4;
      int kb8 = j * 2 + (q >> 1);
#pragma unroll
      for (int i = 0; i < 2; ++i) {
        int qrow = w * 32 + i * 16 + lrow;
        float p[4];
#pragma unroll
        for (int r = 0; r < 4; ++r) {
          float sv = (i == 0) ? s0[r] : s1[r];
          float wp = __builtin_amdgcn_exp2f(__builtin_fmaf(sv, c1, -1.0f));
          float e = wp * 0.0009765625f;
          float t1 = __builtin_fmaf(e, e, -e);  // e^2 - e
          p[r] = __builtin_fmaf(wp, t1, wp);    // wp*(1 - e + e^2)
        }
        *(f16x4*)(Ps + qrow * 128 + ((kb8 ^ (qrow & 15)) << 3) + (kbase & 7)) =
            pack4(p[0], p[1], p[2], p[3]);
      }
    }

    // O += P @ V for own rows (no barrier: Ps rows are wave-local)
#pragma unroll
    for (int ks = 0; ks < 4; ++ks) {
      int m0r = w * 32 + lrow, m1r = m0r + 16;
      f16x8 pa0 = *(const f16x8*)(Ps + m0r * 128 + (((ks * 4 + q) ^ (m0r & 15)) << 3));
      f16x8 pa1 = *(const f16x8*)(Ps + m1r * 128 + (((ks * 4 + q) ^ (m1r & 15)) << 3));
      f16x8 vb[4];
#pragma unroll
      for (int j2 = 0; j2 < 4; ++j2) {
        int n = j2 * 16 + lrow;
        vb[j2] = *(const f16x8*)(Vts + n * 128 + (((ks * 4 + q) ^ (n & 15)) << 3));
      }
#pragma unroll
      for (int j2 = 0; j2 < 4; ++j2) {
        oacc[0][j2] = __builtin_amdgcn_mfma_f32_16x16x32_f16(pa0, vb[j2], oacc[0][j2], 0, 0, 0);
        oacc[1][j2] = __builtin_amdgcn_mfma_f32_16x16x32_f16(pa1, vb[j2], oacc[1][j2], 0, 0, 0);
      }
    }
  }

  // epilogue: descale, bounce through Ps region, coalesced 128B row stores
  barrier_lds();      // all waves' PV reads done before Ob overwrite
  _Float16* Ob = Ps;  // [128][72]
#pragma unroll
  for (int i2 = 0; i2 < 2; ++i2) {
#pragma unroll
    for (int j2 = 0; j2 < 4; ++j2) {
      int d = j2 * 16 + lrow;
#pragma unroll
      for (int r = 0; r < 4; ++r) {
        int row = w * 32 + i2 * 16 + q * 4 + r;
        Ob[row * 72 + d] = (_Float16)(oacc[i2][j2][r] * 0.0009765625f);
      }
    }
  }
  barrier_lds();
#pragma unroll
  for (int it = 0; it < 8; ++it) {
    int row = it * 16 + (tid >> 4);
    int ch = tid & 15;
    f16x4 v = *(const f16x4*)(Ob + row * 72 + ch * 4);
    *(f16x4*)(Ow + (size_t)(b * SEQ + q0 + row) * 512 + h * 64 + ch * 4) = v;
  }
}

// ---------------- output projection (fp32 out, coalesced) ----------------
__global__ __launch_bounds__(256, 2) void oproj_kernel(
    const _Float16* __restrict__ A, const _Float16* __restrict__ Wo,
    float* __restrict__ out) {
  __shared__ _Float16 As[128 * 64];
  __shared__ _Float16 Bs[128 * 64];
  const int m0 = blockIdx.x * 128, n0 = blockIdx.y * 128;
  f32x4 acc[4][4];
  gemm_tile_bt(A, Wo, m0, n0, As, Bs, acc);

  const int tid = threadIdx.x, w = tid >> 6, lane = tid & 63;
  const int wr = w >> 1, wc = w & 1, lcol = lane & 15, q = lane >> 4;
#pragma unroll
  for (int i = 0; i < 4; ++i) {
    int gm0 = m0 + wr * 64 + i * 16 + q * 4;
#pragma unroll
    for (int j = 0; j < 4; ++j) {
      int gn = n0 + wc * 64 + j * 16 + lcol;
#pragma unroll
      for (int r = 0; r < 4; ++r)
        out[(size_t)(gm0 + r) * 512 + gn] = acc[i][j][r];
    }
  }
}

// ---------------- launch ----------------
extern "C" void kernel_launch(void* const* d_in, const int* in_sizes, int n_in,
                              void* d_out, int out_size, void* d_ws, size_t ws_size,
                              hipStream_t stream) {
  const float* x = (const float*)d_in[0];
  const float* Wq = (const float*)d_in[1];
  const float* Wk = (const float*)d_in[2];
  const float* Wv = (const float*)d_in[3];
  const float* Wo = (const float*)d_in[4];
  float* out = (float*)d_out;
  char* ws = (char*)d_ws;

  _Float16* xh = (_Float16*)(ws + 0);          // 8 MB [8192][512]
  _Float16* wh = (_Float16*)(ws + 8388608);    // 4 x 512 KB (q,k,v,o)
  _Float16* Qw = (_Float16*)(ws + 10485760);   // 8 MB [8192][512]
  _Float16* Kw = (_Float16*)(ws + 18874368);   // 8 MB [8192][512]
  _Float16* Vtw = (_Float16*)(ws + 27262976);  // 8 MB [B,H,D,S]
  _Float16* Ow = (_Float16*)(ws + 35651584);   // 8 MB [8192][512]

  _Float16* wqh = wh;
  _Float16* wkh = wh + 262144;
  _Float16* wvh = wh + 524288;
  _Float16* woh = wh + 786432;

  cvt_all_kernel<<<5120, 256, 0, stream>>>(x, Wq, Wk, Wv, Wo, xh, wh);
  qkv_kernel<<<dim3(64, 4, 3), 256, 0, stream>>>(xh, wqh, wkh, wvh, Qw, Kw, Vtw);
  attn_kernel<<<512, 256, 0, stream>>>(Qw, Kw, Vtw, Ow);
  oproj_kernel<<<dim3(64, 4), 256, 0, stream>>>(Ow, woh, out);
}

// Round 8
// 152.502 us; speedup vs baseline: 1.1733x; 1.0035x over previous
//
#include <hip/hip_runtime.h>
#include <stdint.h>

// ---- types ----
typedef _Float16 f16x8 __attribute__((ext_vector_type(8)));
typedef _Float16 f16x4 __attribute__((ext_vector_type(4)));
typedef __fp16 h16x2 __attribute__((ext_vector_type(2)));  // cvt_pkrtz return type
typedef float f32x4 __attribute__((ext_vector_type(4)));

#define SEQ 2048
#define NHEADS 8

// async global->LDS, 16B per lane, LDS dest = wave-uniform base + lane*16
#define GLOAD_LDS16(gp, lp)                                                        \
  __builtin_amdgcn_global_load_lds(                                                \
      (const __attribute__((address_space(1))) void*)(uintptr_t)(const void*)(gp), \
      (__attribute__((address_space(3))) void*)(uintptr_t)(void*)(lp), 16, 0, 0)

// barrier that waits LDS ops only (no vmem drain)
__device__ __forceinline__ void barrier_lds() {
  __builtin_amdgcn_s_waitcnt(0xc07f);  // lgkmcnt(0)
  __builtin_amdgcn_s_barrier();
}

__device__ __forceinline__ f16x4 pack4(float a, float b, float c, float d) {
  h16x2 lo = __builtin_amdgcn_cvt_pkrtz(a, b);
  h16x2 hi = __builtin_amdgcn_cvt_pkrtz(c, d);
  f16x4 o;
  o.x = (_Float16)lo.x; o.y = (_Float16)lo.y;
  o.z = (_Float16)hi.x; o.w = (_Float16)hi.y;
  return o;
}

// ---------------- fp32 -> f16 convert (x + 4 weights, one launch) ----------------
__global__ void cvt_all_kernel(const float* __restrict__ x, const float* __restrict__ wq,
                               const float* __restrict__ wk, const float* __restrict__ wv,
                               const float* __restrict__ wo, _Float16* __restrict__ xh,
                               _Float16* __restrict__ wh) {
  int i = blockIdx.x * 256 + threadIdx.x;  // 0 .. 1310719 (f4 units)
  const float* src;
  _Float16* dst;
  int off;
  if (i < 1048576) {
    src = x; dst = xh; off = i;
  } else {
    int j = i - 1048576;
    int sel = j >> 16;
    off = j & 65535;
    src = (sel == 0) ? wq : (sel == 1) ? wk : (sel == 2) ? wv : wo;
    dst = wh + (size_t)sel * 262144;
  }
  float4 v = ((const float4*)src)[off];
  ((f16x4*)dst)[off] = pack4(v.x, v.y, v.z, v.w);
}

// ---------------- shared 128x128 B^T GEMM tile core (f16, double-buffered DMA) ----------------
// lds = 64 KB: buf b at lds + b*16384: As[128][64], Bs[128][64].
// One __syncthreads per kt; next tile's DMA in flight across the whole compute.
__device__ __forceinline__ void gemm_tile_bt(const _Float16* __restrict__ A,
                                             const _Float16* __restrict__ B,
                                             int m0, int n0,
                                             _Float16* lds,
                                             f32x4 (&acc)[4][4]) {
  const int tid = threadIdx.x;
  const int w = tid >> 6, lane = tid & 63;
  const int wr = w >> 1, wc = w & 1;
  const int lrow = lane & 15, q = lane >> 4;
  const int snb = w * 32 + (lane >> 3);
  const int scb = lane & 7;

#pragma unroll
  for (int i = 0; i < 4; ++i)
#pragma unroll
    for (int j = 0; j < 4; ++j)
#pragma unroll
      for (int r = 0; r < 4; ++r) acc[i][j][r] = 0.f;

  // issue kt=0 staging
#pragma unroll
  for (int t = 0; t < 4; ++t) {
    int n = snb + t * 8;
    int cbg = scb ^ (n & 7);
    GLOAD_LDS16(A + (size_t)(m0 + n) * 512 + cbg * 8, lds + (w * 32 + t * 8) * 64);
    GLOAD_LDS16(B + (size_t)(n0 + n) * 512 + cbg * 8, lds + 8192 + (w * 32 + t * 8) * 64);
  }

  for (int kt = 0; kt < 8; ++kt) {  // K=512, BK=64
    __syncthreads();  // kt's DMA landed; prior reads of this buf done
    if (kt < 7) {
      _Float16* nb = lds + ((kt + 1) & 1) * 16384;
#pragma unroll
      for (int t = 0; t < 4; ++t) {
        int n = snb + t * 8;
        int cbg = scb ^ (n & 7);
        GLOAD_LDS16(A + (size_t)(m0 + n) * 512 + (kt + 1) * 64 + cbg * 8, nb + (w * 32 + t * 8) * 64);
        GLOAD_LDS16(B + (size_t)(n0 + n) * 512 + (kt + 1) * 64 + cbg * 8, nb + 8192 + (w * 32 + t * 8) * 64);
      }
    }
    _Float16* As = lds + (kt & 1) * 16384;
    _Float16* Bs = As + 8192;

    f16x8 af[4][2], bfr[4][2];
#pragma unroll
    for (int i = 0; i < 4; ++i) {
      int m = wr * 64 + i * 16 + lrow;
#pragma unroll
      for (int kk = 0; kk < 2; ++kk) {
        int cb = (kk * 4 + q) ^ (m & 7);
        af[i][kk] = *(const f16x8*)(As + m * 64 + cb * 8);
      }
    }
#pragma unroll
    for (int j = 0; j < 4; ++j) {
      int n = wc * 64 + j * 16 + lrow;
#pragma unroll
      for (int kk = 0; kk < 2; ++kk) {
        int cb = (kk * 4 + q) ^ (n & 7);
        bfr[j][kk] = *(const f16x8*)(Bs + n * 64 + cb * 8);
      }
    }
#pragma unroll
    for (int i = 0; i < 4; ++i)
#pragma unroll
      for (int j = 0; j < 4; ++j) {
        acc[i][j] = __builtin_amdgcn_mfma_f32_16x16x32_f16(af[i][0], bfr[j][0], acc[i][j], 0, 0, 0);
        acc[i][j] = __builtin_amdgcn_mfma_f32_16x16x32_f16(af[i][1], bfr[j][1], acc[i][j], 0, 0, 0);
      }
  }
}

// ---------------- QKV projection (768 blocks, coalesced bounce epilogues) ----------------
__global__ __launch_bounds__(256, 2) void qkv_kernel(
    const _Float16* __restrict__ xb, const _Float16* __restrict__ Wq,
    const _Float16* __restrict__ Wk, const _Float16* __restrict__ Wv,
    _Float16* __restrict__ Qo, _Float16* __restrict__ Ko, _Float16* __restrict__ Vto) {
  __shared__ _Float16 pool[32768];  // 64 KB dbuf staging; bounce [128][136] aliases
  const int z = blockIdx.z;
  f32x4 acc[4][4];
  const int tid = threadIdx.x, w = tid >> 6, lane = tid & 63;
  const int wr = w >> 1, wc = w & 1, lcol = lane & 15, q = lane >> 4;

  if (z < 2) {
    const int m0 = blockIdx.y * 128;  // out-feature tile
    const int n0 = blockIdx.x * 128;  // s tile
    gemm_tile_bt((z == 0) ? Wq : Wk, xb, m0, n0, pool, acc);
    _Float16* outp = (z == 0) ? Qo : Ko;
    __syncthreads();  // all reads done; reuse pool as bounce [s 128][c 136]
#pragma unroll
    for (int i = 0; i < 4; ++i) {
      int cl = wr * 64 + i * 16 + q * 4;
#pragma unroll
      for (int j = 0; j < 4; ++j) {
        int s = wc * 64 + j * 16 + lcol;
        *(f16x4*)(pool + s * 136 + cl) =
            pack4(acc[i][j][0], acc[i][j][1], acc[i][j][2], acc[i][j][3]);
      }
    }
    __syncthreads();
#pragma unroll
    for (int it = 0; it < 16; ++it) {
      int srow = it * 8 + (tid >> 5);
      int ch = tid & 31;
      f16x4 v = *(const f16x4*)(pool + srow * 136 + ch * 4);
      *(f16x4*)(outp + (size_t)(n0 + srow) * 512 + m0 + ch * 4) = v;
    }
  } else {
    const int m0 = blockIdx.x * 128;  // s tile
    const int n0 = blockIdx.y * 128;  // feature tile
    gemm_tile_bt(xb, Wv, m0, n0, pool, acc);
    const int bb = m0 >> 11, sl0 = m0 & 2047;
    __syncthreads();  // bounce [c 128][s 136]
#pragma unroll
    for (int i = 0; i < 4; ++i) {
      int s0 = wr * 64 + i * 16 + q * 4;
#pragma unroll
      for (int j = 0; j < 4; ++j) {
        int c = wc * 64 + j * 16 + lcol;
        *(f16x4*)(pool + c * 136 + s0) =
            pack4(acc[i][j][0], acc[i][j][1], acc[i][j][2], acc[i][j][3]);
      }
    }
    __syncthreads();
#pragma unroll
    for (int it = 0; it < 16; ++it) {
      int crow = it * 8 + (tid >> 5);
      int ch = tid & 31;
      int cg = n0 + crow, h = cg >> 6, d = cg & 63;
      f16x4 v = *(const f16x4*)(pool + crow * 136 + ch * 4);
      *(f16x4*)(Vto + ((size_t)((bb * NHEADS + h) * 64 + d)) * SEQ + sl0 + ch * 4) = v;
    }
  }
}

// ---------------- sigmoid attention: register-resident P, dbuf K/V, 1 barrier/kt ----------------
// Wave owns 32 q-rows. S^T C-layout == 16x16x16 A-frag layout, so sigmoid output
// feeds PV straight from registers. K/V double-buffered; DMA for kt+1 issued right
// after the barrier -> full compute phase to land.
__global__ __launch_bounds__(256, 2) void attn_kernel(
    const _Float16* __restrict__ Qw, const _Float16* __restrict__ Kw,
    const _Float16* __restrict__ Vtw, _Float16* __restrict__ Ow) {
  __shared__ _Float16 lds[32768];  // 64 KB: buf b at lds+b*16384: Ks[128][64], Vts[64][128]

  const int tid = threadIdx.x, w = tid >> 6, lane = tid & 63;
  const int lrow = lane & 15, q = lane >> 4;

  // XCD swizzle: 4 bh x 16 q-tiles per XCD (K/V stay L2-resident)
  const int L = blockIdx.x;
  const int xcd = L & 7, slot = L >> 3;
  const int bh = xcd * 4 + (slot >> 4), qt = slot & 15;
  const int b = bh >> 3, h = bh & 7;
  const int q0 = qt * 128;

  const _Float16* Qp = Qw + ((size_t)(b * SEQ + q0)) * 512 + h * 64;
  const _Float16* Kp = Kw + ((size_t)b * SEQ) * 512 + h * 64;
  const _Float16* Vp = Vtw + (size_t)bh * 64 * SEQ;

  const int snb = w * 32 + (lane >> 3), scb = lane & 7;   // [128][64] staging
  const int vnb = w * 16 + (lane >> 4), vcb = lane & 15;  // [64][128] staging

  // stage Q tile [128][64] into buf0's Ks region
  _Float16* Qs = lds;
#pragma unroll
  for (int t = 0; t < 4; ++t) {
    int n = snb + t * 8;
    int cbg = scb ^ (n & 7);
    GLOAD_LDS16(Qp + (size_t)n * 512 + cbg * 8, Qs + (w * 32 + t * 8) * 64);
  }
  __syncthreads();

  // wave's own 32 q-rows
  f16x8 qa[2][2];
#pragma unroll
  for (int i = 0; i < 2; ++i) {
    int m = w * 32 + i * 16 + lrow;
#pragma unroll
    for (int kk = 0; kk < 2; ++kk) {
      int cb = (kk * 4 + q) ^ (m & 7);
      qa[i][kk] = *(const f16x8*)(Qs + m * 64 + cb * 8);
    }
  }
  barrier_lds();  // all qa reads done before buf0 DMA overwrite

  // issue kt=0 staging into buf0
#pragma unroll
  for (int t = 0; t < 4; ++t) {
    int n = snb + t * 8;
    int cbg = scb ^ (n & 7);
    GLOAD_LDS16(Kp + (size_t)n * 512 + cbg * 8, lds + (w * 32 + t * 8) * 64);
  }
#pragma unroll
  for (int t = 0; t < 4; ++t) {
    int nv = vnb + t * 4;
    int cbg = vcb ^ (nv & 15);
    GLOAD_LDS16(Vp + (size_t)nv * SEQ + cbg * 8, lds + 8192 + (w * 16 + t * 4) * 128);
  }

  f32x4 oacc[2][4];
#pragma unroll
  for (int i = 0; i < 2; ++i)
#pragma unroll
    for (int j = 0; j < 4; ++j)
#pragma unroll
      for (int r = 0; r < 4; ++r) oacc[i][j][r] = 0.f;

  const float c1 = 0.18033688011112042f;  // (1/8)*log2(e); exp2 bias -1 = -11+10 (P x1024)

  for (int kt = 0; kt < 16; ++kt) {
    __syncthreads();  // kt's DMA landed (issued one iter ago); prev buf reads done
    if (kt < 15) {
      _Float16* nb = lds + ((kt + 1) & 1) * 16384;
#pragma unroll
      for (int t = 0; t < 4; ++t) {
        int n = snb + t * 8;
        int cbg = scb ^ (n & 7);
        GLOAD_LDS16(Kp + (size_t)((kt + 1) * 128 + n) * 512 + cbg * 8, nb + (w * 32 + t * 8) * 64);
      }
#pragma unroll
      for (int t = 0; t < 4; ++t) {
        int nv = vnb + t * 4;
        int cbg = vcb ^ (nv & 15);
        GLOAD_LDS16(Vp + (size_t)nv * SEQ + (kt + 1) * 128 + cbg * 8, nb + 8192 + (w * 16 + t * 4) * 128);
      }
    }
    _Float16* Ksc = lds + (kt & 1) * 16384;
    _Float16* Vtsc = Ksc + 8192;

    // per 16-kcol block j: QK^T (S^T form) -> sigmoid in regs -> PV via 16x16x16
#pragma unroll
    for (int j = 0; j < 8; ++j) {
      int n = j * 16 + lrow;
      f16x8 k0 = *(const f16x8*)(Ksc + n * 64 + ((q ^ (n & 7)) << 3));
      f16x8 k1 = *(const f16x8*)(Ksc + n * 64 + (((4 + q) ^ (n & 7)) << 3));
      f32x4 s0, s1;
#pragma unroll
      for (int r = 0; r < 4; ++r) { s0[r] = 0.f; s1[r] = 0.f; }
      s0 = __builtin_amdgcn_mfma_f32_16x16x32_f16(k0, qa[0][0], s0, 0, 0, 0);
      s0 = __builtin_amdgcn_mfma_f32_16x16x32_f16(k1, qa[0][1], s0, 0, 0, 0);
      s1 = __builtin_amdgcn_mfma_f32_16x16x32_f16(k0, qa[1][0], s1, 0, 0, 0);
      s1 = __builtin_amdgcn_mfma_f32_16x16x32_f16(k1, qa[1][1], s1, 0, 0, 0);

      float p0[4], p1[4];
#pragma unroll
      for (int r = 0; r < 4; ++r) {
        float wp = __builtin_amdgcn_exp2f(__builtin_fmaf(s0[r], c1, -1.0f));
        float e = wp * 0.0009765625f;
        p0[r] = __builtin_fmaf(wp, __builtin_fmaf(e, e, -e), wp);  // wp*(1-e+e^2)
        float wp1 = __builtin_amdgcn_exp2f(__builtin_fmaf(s1[r], c1, -1.0f));
        float e1 = wp1 * 0.0009765625f;
        p1[r] = __builtin_fmaf(wp1, __builtin_fmaf(e1, e1, -e1), wp1);
      }
      f16x4 pf0 = pack4(p0[0], p0[1], p0[2], p0[3]);
      f16x4 pf1 = pack4(p1[0], p1[1], p1[2], p1[3]);

      // PV: O[m=qrow][d] += P[m][j*16+q*4+r] * V[k][d]; B-frag b64 reads (conflict-free)
#pragma unroll
      for (int j2 = 0; j2 < 4; ++j2) {
        int nv = j2 * 16 + lrow;
        int cb = (j * 2 + (q >> 1)) ^ (nv & 15);
        f16x4 vb = *(const f16x4*)(Vtsc + nv * 128 + (cb << 3) + ((q & 1) << 2));
        oacc[0][j2] = __builtin_amdgcn_mfma_f32_16x16x16f16(pf0, vb, oacc[0][j2], 0, 0, 0);
        oacc[1][j2] = __builtin_amdgcn_mfma_f32_16x16x16f16(pf1, vb, oacc[1][j2], 0, 0, 0);
      }
    }
  }

  // epilogue: descale, bounce through LDS, coalesced 128B row stores
  barrier_lds();      // all waves' LDS reads done; no DMA outstanding (kt=15 skipped)
  _Float16* Ob = lds;  // [128][72]
#pragma unroll
  for (int i2 = 0; i2 < 2; ++i2) {
#pragma unroll
    for (int j2 = 0; j2 < 4; ++j2) {
      int d = j2 * 16 + lrow;
#pragma unroll
      for (int r = 0; r < 4; ++r) {
        int row = w * 32 + i2 * 16 + q * 4 + r;
        Ob[row * 72 + d] = (_Float16)(oacc[i2][j2][r] * 0.0009765625f);
      }
    }
  }
  barrier_lds();
#pragma unroll
  for (int it = 0; it < 8; ++it) {
    int row = it * 16 + (tid >> 4);
    int ch = tid & 15;
    f16x4 v = *(const f16x4*)(Ob + row * 72 + ch * 4);
    *(f16x4*)(Ow + (size_t)(b * SEQ + q0 + row) * 512 + h * 64 + ch * 4) = v;
  }
}

// ---------------- output projection (fp32 out, coalesced) ----------------
__global__ __launch_bounds__(256, 2) void oproj_kernel(
    const _Float16* __restrict__ A, const _Float16* __restrict__ Wo,
    float* __restrict__ out) {
  __shared__ _Float16 pool[32768];  // 64 KB dbuf
  const int m0 = blockIdx.x * 128, n0 = blockIdx.y * 128;
  f32x4 acc[4][4];
  gemm_tile_bt(A, Wo, m0, n0, pool, acc);

  const int tid = threadIdx.x, w = tid >> 6, lane = tid & 63;
  const int wr = w >> 1, wc = w & 1, lcol = lane & 15, q = lane >> 4;
#pragma unroll
  for (int i = 0; i < 4; ++i) {
    int gm0 = m0 + wr * 64 + i * 16 + q * 4;
#pragma unroll
    for (int j = 0; j < 4; ++j) {
      int gn = n0 + wc * 64 + j * 16 + lcol;
#pragma unroll
      for (int r = 0; r < 4; ++r)
        out[(size_t)(gm0 + r) * 512 + gn] = acc[i][j][r];
    }
  }
}

// ---------------- launch ----------------
extern "C" void kernel_launch(void* const* d_in, const int* in_sizes, int n_in,
                              void* d_out, int out_size, void* d_ws, size_t ws_size,
                              hipStream_t stream) {
  const float* x = (const float*)d_in[0];
  const float* Wq = (const float*)d_in[1];
  const float* Wk = (const float*)d_in[2];
  const float* Wv = (const float*)d_in[3];
  const float* Wo = (const float*)d_in[4];
  float* out = (float*)d_out;
  char* ws = (char*)d_ws;

  _Float16* xh = (_Float16*)(ws + 0);          // 8 MB [8192][512]
  _Float16* wh = (_Float16*)(ws + 8388608);    // 4 x 512 KB (q,k,v,o)
  _Float16* Qw = (_Float16*)(ws + 10485760);   // 8 MB [8192][512]
  _Float16* Kw = (_Float16*)(ws + 18874368);   // 8 MB [8192][512]
  _Float16* Vtw = (_Float16*)(ws + 27262976);  // 8 MB [B,H,D,S]
  _Float16* Ow = (_Float16*)(ws + 35651584);   // 8 MB [8192][512]

  _Float16* wqh = wh;
  _Float16* wkh = wh + 262144;
  _Float16* wvh = wh + 524288;
  _Float16* woh = wh + 786432;

  cvt_all_kernel<<<5120, 256, 0, stream>>>(x, Wq, Wk, Wv, Wo, xh, wh);
  qkv_kernel<<<dim3(64, 4, 3), 256, 0, stream>>>(xh, wqh, wkh, wvh, Qw, Kw, Vtw);
  attn_kernel<<<512, 256, 0, stream>>>(Qw, Kw, Vtw, Ow);
  oproj_kernel<<<dim3(64, 4), 256, 0, stream>>>(Ow, woh, out);
}